// Round 9
// baseline (496.308 us; speedup 1.0000x reference)
//
#include <hip/hip_runtime.h>
#include <cstddef>

#define Bx 2
#define Tn 4096
#define Hh 8

typedef unsigned short u16;
typedef unsigned int u32;
typedef __attribute__((ext_vector_type(8))) short short8;
typedef __attribute__((ext_vector_type(4))) float f32x4;

__device__ __forceinline__ float bf2f(u16 u) {
  u32 x = ((u32)u) << 16;
  return __uint_as_float(x);
}
__device__ __forceinline__ u16 f2bf(float f) {
  u32 x = __float_as_uint(f);
  u32 lsb = (x >> 16) & 1;
  x += 0x7fffu + lsb;
  return (u16)(x >> 16);
}
__device__ __forceinline__ u32 pack2(float a, float b) {
  return (u32)f2bf(a) | ((u32)f2bf(b) << 16);
}
__device__ __forceinline__ short8 cvt8(float4 f0, float4 f1) {
  uint4 p;
  p.x = pack2(f0.x, f0.y);
  p.y = pack2(f0.z, f0.w);
  p.z = pack2(f1.x, f1.y);
  p.w = pack2(f1.z, f1.w);
  return *(short8*)&p;
}
__device__ __forceinline__ void async16(u16* lds, const u16* g) {
  __builtin_amdgcn_global_load_lds((const __attribute__((address_space(1))) void*)g,
                                   (__attribute__((address_space(3))) void*)lds, 16, 0, 0);
}

// ---------------------------------------------------------------------------
// f32 -> bf16 elementwise convert
// ---------------------------------------------------------------------------
__global__ __launch_bounds__(256) void conv_bf16(const float* __restrict__ X,
                                                 u16* __restrict__ Xb) {
  int i = (blockIdx.x * 256 + threadIdx.x) * 8;
  float4 v0 = *(const float4*)&X[i];
  float4 v1 = *(const float4*)&X[i + 4];
  uint4 pv;
  pv.x = pack2(v0.x, v0.y);
  pv.y = pack2(v0.z, v0.w);
  pv.z = pack2(v1.x, v1.y);
  pv.w = pack2(v1.z, v1.w);
  *(uint4*)&Xb[i] = pv;
}

// ---------------------------------------------------------------------------
// Transpose-convert: W[K][N] f32 -> WT[N][K] bf16. 64x64 tiles.
// ---------------------------------------------------------------------------
__global__ __launch_bounds__(256) void transpose_bf16(const float* __restrict__ W,
                                                      u16* __restrict__ WT,
                                                      int K, int N) {
  __shared__ float tile[64][68];
  int nb = blockIdx.x, kb = blockIdx.y;
  int tid = threadIdx.x;
  int r = tid >> 4, c4 = (tid & 15) * 4;
#pragma unroll
  for (int p = 0; p < 4; p++) {
    int k = kb * 64 + p * 16 + r;
    float4 v = *(const float4*)&W[(size_t)k * N + nb * 64 + c4];
    tile[p * 16 + r][c4] = v.x;
    tile[p * 16 + r][c4 + 1] = v.y;
    tile[p * 16 + r][c4 + 2] = v.z;
    tile[p * 16 + r][c4 + 3] = v.w;
  }
  __syncthreads();
  int rn = tid >> 2, ck = (tid & 3) * 16;
#pragma unroll
  for (int s = 0; s < 2; s++) {
    int k0 = ck + s * 8;
    uint4 pv;
    pv.x = pack2(tile[k0 + 0][rn], tile[k0 + 1][rn]);
    pv.y = pack2(tile[k0 + 2][rn], tile[k0 + 3][rn]);
    pv.z = pack2(tile[k0 + 4][rn], tile[k0 + 5][rn]);
    pv.w = pack2(tile[k0 + 6][rn], tile[k0 + 7][rn]);
    *(uint4*)&WT[(size_t)(nb * 64 + rn) * K + kb * 64 + k0] = pv;
  }
}

// ---------------------------------------------------------------------------
// gemm_qkvz: 256x256-tile deep-pipelined bf16 GEMM (guide §5 8-phase family).
// M=8192, N=4096, K=1024. 8 waves (2M x 4N), 512 thr, BK=64.
// LDS 128 KiB dynamic, XOR-swizzled, double-buffered; one drain per K-tile.
// ---------------------------------------------------------------------------
__global__ __launch_bounds__(512, 1) void gemm_qkvz(const u16* __restrict__ A,
                                                    const u16* __restrict__ Bt,
                                                    u16* __restrict__ O1,
                                                    u16* __restrict__ O2) {
  const int K = 1024;
  extern __shared__ __align__(16) u16 gl[];  // As[2]: 0,16384; Bs[2]: 32768,49152
  int lin = blockIdx.x;
  int sl = (lin & 7) * 64 + (lin >> 3);  // 512 blocks, 64 per XCD
  int bm = sl & 31;                      // 32 M-tiles (8192/256)
  int bn = sl >> 5;                      // 16 N-tiles (4096/256); 2 per XCD
  int tid = threadIdx.x;
  int wid = tid >> 6, lane = tid & 63;
  int wm = wid >> 2, wn = wid & 3;
  int m_lane = lane & 15, kgrp = lane >> 4, m7 = m_lane & 7;

  f32x4 acc[8][4];
#pragma unroll
  for (int i = 0; i < 8; i++)
#pragma unroll
    for (int j = 0; j < 4; j++) acc[i][j] = (f32x4){0.f, 0.f, 0.f, 0.f};

  int srow = lane >> 3;
  int gc8 = ((lane & 7) ^ srow) * 8;
  const u16* Ab = A + (size_t)(bm * 256 + wid * 32 + srow) * K + gc8;
  const u16* Bb = Bt + (size_t)(bn * 256 + wid * 32 + srow) * K + gc8;

  // prologue: stage tile 0 into buffer 0
#pragma unroll
  for (int i = 0; i < 4; i++) {
    async16(gl + (wid * 32 + i * 8) * 64, Ab + (size_t)(i * 8) * K);
    async16(gl + 32768 + (wid * 32 + i * 8) * 64, Bb + (size_t)(i * 8) * K);
  }
  asm volatile("s_waitcnt vmcnt(0)" ::: "memory");
  __builtin_amdgcn_s_barrier();

  for (int t = 0; t < 16; t++) {
    int p = t & 1;
    const u16* Ap = gl + p * 16384;
    const u16* Bp = gl + 32768 + p * 16384;
    if (t < 15) {
      int pn = p ^ 1;
      int kk = (t + 1) * 64;
#pragma unroll
      for (int i = 0; i < 4; i++) {
        async16(gl + pn * 16384 + (wid * 32 + i * 8) * 64, Ab + (size_t)(i * 8) * K + kk);
        async16(gl + 32768 + pn * 16384 + (wid * 32 + i * 8) * 64, Bb + (size_t)(i * 8) * K + kk);
      }
    }
    short8 bq[2][4];
#pragma unroll
    for (int ks = 0; ks < 2; ks++)
#pragma unroll
      for (int nf = 0; nf < 4; nf++)
        bq[ks][nf] = *(const short8*)&Bp[(wn * 64 + nf * 16 + m_lane) * 64 +
                                         (((ks * 4 + kgrp) ^ m7) << 3)];
#pragma unroll
    for (int mf = 0; mf < 8; mf++) {
      short8 aq0 = *(const short8*)&Ap[(wm * 128 + mf * 16 + m_lane) * 64 +
                                       ((kgrp ^ m7) << 3)];
      short8 aq1 = *(const short8*)&Ap[(wm * 128 + mf * 16 + m_lane) * 64 +
                                       (((4 + kgrp) ^ m7) << 3)];
#pragma unroll
      for (int nf = 0; nf < 4; nf++)
        acc[mf][nf] = __builtin_amdgcn_mfma_f32_16x16x32_bf16(aq0, bq[0][nf], acc[mf][nf], 0, 0, 0);
#pragma unroll
      for (int nf = 0; nf < 4; nf++)
        acc[mf][nf] = __builtin_amdgcn_mfma_f32_16x16x32_bf16(aq1, bq[1][nf], acc[mf][nf], 0, 0, 0);
    }
    if (t < 15) {
      asm volatile("s_waitcnt vmcnt(0) lgkmcnt(0)" ::: "memory");
      __builtin_amdgcn_s_barrier();
      __builtin_amdgcn_sched_barrier(0);
    }
  }

  int n0w = bn * 256 + wn * 64;
  int h = n0w >> 9, sub = (n0w >> 7) & 3;
  int cin = ((n0w & 127) & 64) + m_lane;
  u16* dst;
  size_t stride;
  if (sub < 3) { dst = O1 + (size_t)(sub * 1024 + h * 128); stride = 3072; }
  else         { dst = O2 + (size_t)(h * 128);              stride = 1024; }
  int rbase = bm * 256 + wm * 128 + kgrp * 4;
#pragma unroll
  for (int mf = 0; mf < 8; mf++)
#pragma unroll
    for (int nf = 0; nf < 4; nf++)
#pragma unroll
      for (int r = 0; r < 4; r++)
        dst[(size_t)(rbase + mf * 16 + r) * stride + cin + nf * 16] = f2bf(acc[mf][nf][r]);
}

// ---------------------------------------------------------------------------
// bf16 MFMA GEMM v2 (128x128, BK=64, swizzled, XCD remap) — used for out GEMM.
// EPI=0: f32 store.
// ---------------------------------------------------------------------------
template<int EPI>
__global__ __launch_bounds__(256) void gemm_mfma(const u16* __restrict__ A,
                                                 const u16* __restrict__ Bt,
                                                 u16* __restrict__ O1,
                                                 u16* __restrict__ O2,
                                                 float* __restrict__ O3,
                                                 int Nfull) {
  const int K = 1024;
  __shared__ u16 As[128 * 64];
  __shared__ u16 Bs[128 * 64];
  int lin = blockIdx.y * gridDim.x + blockIdx.x;
  int sl = lin >> 3;
  int cbn = gridDim.x >> 3;
  int bn = (lin & 7) * cbn + (sl % cbn);
  int bm = sl / cbn;
  int tid = threadIdx.x;
  int wave = tid >> 6, lane = tid & 63;
  int wr = wave >> 1, wc = wave & 1;

  f32x4 acc[4][4];
#pragma unroll
  for (int i = 0; i < 4; i++)
#pragma unroll
    for (int j = 0; j < 4; j++) acc[i][j] = (f32x4){0.f, 0.f, 0.f, 0.f};

  int srow = lane >> 3;
  int gc8 = ((lane & 7) ^ srow) * 8;
  const u16* Ab = A + (size_t)(bm * 128 + wave * 32 + srow) * K + gc8;
  const u16* Bb = Bt + (size_t)(bn * 128 + wave * 32 + srow) * K + gc8;
  u16* AsW = &As[(wave * 32) * 64];
  u16* BsW = &Bs[(wave * 32) * 64];

  int m_lane = lane & 15, kgrp = lane >> 4;
  int m7 = m_lane & 7;

  for (int kk = 0; kk < K; kk += 64) {
    __syncthreads();
#pragma unroll
    for (int i = 0; i < 4; i++) {
      async16(AsW + i * 512, Ab + (size_t)(i * 8) * K + kk);
      async16(BsW + i * 512, Bb + (size_t)(i * 8) * K + kk);
    }
    __syncthreads();
    short8 a[4][2], b[4][2];
#pragma unroll
    for (int t = 0; t < 4; t++)
#pragma unroll
      for (int ks = 0; ks < 2; ks++) {
        a[t][ks] = *(const short8*)&As[(wr * 64 + t * 16 + m_lane) * 64 +
                                       (((ks * 4 + kgrp) ^ m7) << 3)];
        b[t][ks] = *(const short8*)&Bs[(wc * 64 + t * 16 + m_lane) * 64 +
                                       (((ks * 4 + kgrp) ^ m7) << 3)];
      }
#pragma unroll
    for (int ks = 0; ks < 2; ks++)
#pragma unroll
      for (int i = 0; i < 4; i++)
#pragma unroll
        for (int j = 0; j < 4; j++)
          acc[i][j] = __builtin_amdgcn_mfma_f32_16x16x32_bf16(a[i][ks], b[j][ks],
                                                              acc[i][j], 0, 0, 0);
  }

  int n0 = bn * 128;
  int cbase = wc * 64 + (lane & 15);
  int rbase = bm * 128 + wr * 64 + ((lane >> 4) * 4);
  if (EPI == 1) {
    int h = n0 >> 9, sub = (n0 >> 7) & 3;
    u16* dst;
    size_t stride;
    if (sub < 3) { dst = O1 + (size_t)(sub * 1024 + h * 128); stride = 3072; }
    else         { dst = O2 + (size_t)(h * 128);              stride = 1024; }
#pragma unroll
    for (int i = 0; i < 4; i++)
#pragma unroll
      for (int j = 0; j < 4; j++)
#pragma unroll
        for (int r = 0; r < 4; r++)
          dst[(size_t)(rbase + i * 16 + r) * stride + cbase + j * 16] = f2bf(acc[i][j][r]);
  } else {
#pragma unroll
    for (int i = 0; i < 4; i++)
#pragma unroll
      for (int j = 0; j < 4; j++)
#pragma unroll
        for (int r = 0; r < 4; r++)
          O3[(size_t)(rbase + i * 16 + r) * Nfull + n0 + cbase + j * 16] = acc[i][j][r];
  }
}

// ---------------------------------------------------------------------------
// ba = x @ W_ba then beta = sigmoid(b), g = -exp(A)*softplus(a+dt)
// ---------------------------------------------------------------------------
__global__ __launch_bounds__(128) void ba_kernel(const float* __restrict__ x,
                                                 const float* __restrict__ Wba,
                                                 const float* __restrict__ dtb,
                                                 const float* __restrict__ Alog,
                                                 float* __restrict__ betab,
                                                 float* __restrict__ gb) {
  __shared__ float xs[1024];
  __shared__ float part[8][16];
  int row = blockIdx.x, tid = threadIdx.x;
#pragma unroll
  for (int r = 0; r < 2; r++) {
    int f4 = r * 128 + tid;
    *(float4*)&xs[f4 * 4] = *(const float4*)&x[(size_t)row * 1024 + f4 * 4];
  }
  __syncthreads();
  int col = tid & 15, seg = tid >> 4;
  float a = 0.f;
  for (int k = seg * 128; k < seg * 128 + 128; k++) a += xs[k] * Wba[k * 16 + col];
  part[seg][col] = a;
  __syncthreads();
  if (tid < 8) {
    float bval = 0.f, aval = 0.f;
#pragma unroll
    for (int q = 0; q < 8; q++) { bval += part[q][tid * 2]; aval += part[q][tid * 2 + 1]; }
    betab[(size_t)row * 8 + tid] = 1.f / (1.f + expf(-bval));
    float spin = aval + dtb[tid];
    float sp = (spin > 20.f) ? spin : log1pf(expf(spin));
    gb[(size_t)row * 8 + tid] = -expf(Alog[tid]) * sp;
  }
}

// ---------------------------------------------------------------------------
// conv+silu+l2norm streaming kernel for q (type 0) and k (type 1).
// ---------------------------------------------------------------------------
__global__ __launch_bounds__(256) void convnorm(const u16* __restrict__ mixed,
                                                const float* __restrict__ cw,
                                                const float* __restrict__ gbuf,
                                                u16* __restrict__ qn,
                                                u16* __restrict__ kn,
                                                u16* __restrict__ kdT) {
  __shared__ __align__(16) u16 sRaw[67 * 128];
  __shared__ __align__(16) u16 sO[64 * 136];
  __shared__ float red_s[256];
  __shared__ float inv_s[64];
  __shared__ float eglc_s[64];
  int n = blockIdx.x, bh = blockIdx.y, type = blockIdx.z;
  int b = bh >> 3, h = bh & 7;
  int t0 = n * 64, tid = threadIdx.x;
  int srow = tid >> 4, scol8 = (tid & 15) * 8;
  int base = type * 1024;  // 0 for q, 1024 for k

  // stage raw slice rows t0-3..t0+63
#pragma unroll
  for (int pass = 0; pass < 5; pass++) {
    int r = pass * 16 + srow;
    if (r < 67) {
      int t = t0 - 3 + r;
      uint4 v = make_uint4(0u, 0u, 0u, 0u);
      if (t >= 0) v = *(const uint4*)&mixed[(size_t)(b * Tn + t) * 3072 + base + h * 128 + scol8];
      *(uint4*)&sRaw[r * 128 + scol8] = v;
    }
  }
  // k-type: cumsum -> eglc = exp(gl - gc_i)
  if (type == 1 && tid < 64) {
    float gv = gbuf[(size_t)(b * Tn + t0 + tid) * 8 + h];
#pragma unroll
    for (int off = 1; off < 64; off <<= 1) {
      float o = __shfl_up(gv, off, 64);
      if (tid >= off) gv += o;
    }
    float gl = __shfl(gv, 63, 64);
    eglc_s[tid] = expf(gl - gv);
  }
  __syncthreads();

  // conv + silu -> sO (bf16)
#pragma unroll
  for (int it = 0; it < 32; it++) {
    int idx = it * 256 + tid;
    int i = idx >> 7, d = idx & 127;
    int colw = (base + h * 128 + d) * 4;
    float a = 0.f;
#pragma unroll
    for (int tap = 0; tap < 4; tap++)
      a += bf2f(sRaw[(i + tap) * 128 + d]) * cw[colw + tap];
    a = a / (1.f + expf(-a));
    sO[i * 136 + d] = f2bf(a);
  }
  __syncthreads();
  // row sumsq
  {
    int i = tid >> 2, p = tid & 3;
    float ss = 0.f;
#pragma unroll
    for (int d = p * 32; d < p * 32 + 32; d += 2) {
      u32 w2 = *(const u32*)&sO[i * 136 + d];
      float a = bf2f(w2 & 0xffff), b2 = bf2f(w2 >> 16);
      ss += a * a + b2 * b2;
    }
    red_s[tid] = ss;
  }
  __syncthreads();
  if (tid < 64) {
    float inv = rsqrtf(red_s[tid * 4] + red_s[tid * 4 + 1] + red_s[tid * 4 + 2] + red_s[tid * 4 + 3] + 1e-6f);
    inv_s[tid] = (type == 0) ? inv * 0.08838834764831845f : inv;
  }
  __syncthreads();
  // normalize + emit row-major (k also writes back to LDS for kdT transpose)
  u16* dstRow = (type == 0 ? qn : kn) + (size_t)(bh * Tn + t0) * 128;
#pragma unroll
  for (int it = 0; it < 16; it++) {
    int idx = it * 256 + tid;
    int i = idx >> 6, d2 = (idx & 63) * 2;
    u32 w2 = *(const u32*)&sO[i * 136 + d2];
    float inv = inv_s[i];
    float q0 = bf2f(w2 & 0xffff) * inv, q1 = bf2f(w2 >> 16) * inv;
    u32 pk = pack2(q0, q1);
    if (type == 1) *(u32*)&sO[i * 136 + d2] = pk;
    *(u32*)&dstRow[(size_t)i * 128 + d2] = pk;
  }
  if (type == 1) {
    __syncthreads();
    const size_t tbase = (size_t)(bh * 64 + n) * 8192;
#pragma unroll
    for (int it = 0; it < 32; it++) {
      int idx = it * 256 + tid;
      int d = idx >> 6, i = idx & 63;
      kdT[tbase + d * 64 + i] = f2bf(bf2f(sO[i * 136 + d]) * eglc_s[i]);
    }
  }
}

// ---------------------------------------------------------------------------
// Per-chunk prep v3: stage normalized qn/kn + raw v, cumsum tables,
// qg emit, MFMA attn/tri, forward substitution, kcum/vnT writes.
// NOTE: kcum is written NEGATED (scan consumes -kcum, saving the S-negate).
// ---------------------------------------------------------------------------
__global__ __launch_bounds__(256) void prep(const u16* __restrict__ mixed,
                                            const float* __restrict__ cw,
                                            const float* __restrict__ gbuf,
                                            const float* __restrict__ betabuf,
                                            u16* qbuf,
                                            u16* kbuf,
                                            u16* __restrict__ vnT,
                                            u16* __restrict__ attn,
                                            float* __restrict__ egl) {
  __shared__ __align__(16) u16 sKn[64 * 136];    // 17408 B
  __shared__ __align__(16) u16 sQn[64 * 136];    // 17408 B; aliased as tri f32[64*64]
  __shared__ __align__(16) u16 sRawV[67 * 128];  // 17152 B raw v slice (halo)
  __shared__ float gc_s[64], egc_s[64], bet_s[64];
  float* triL = (float*)sQn;  // alias: tri written after attn consumed sQn

  int n = blockIdx.x, bh = blockIdx.y;
  int b = bh >> 3, h = bh & 7;
  int t0 = n * 64;
  int tid = threadIdx.x;
  const int rowg0 = b * Tn + t0;
  const int rowh0 = bh * Tn + t0;
  const size_t tbase = (size_t)(bh * 64 + n) * 8192;

  int wv = tid >> 6, lane = tid & 63;
  int m16 = lane & 15, q8 = (lane >> 4) * 8, qr = (lane >> 4) * 4;
  int srow = tid >> 4, scol8 = (tid & 15) * 8;

  // ---- stage qn, kn (padded LDS rows), raw v (halo), tables ----
#pragma unroll
  for (int it = 0; it < 4; it++) {
    int idx = it * 256 + tid;
    int i = idx >> 4, c8 = (idx & 15) * 8;
    *(uint4*)&sQn[i * 136 + c8] = *(const uint4*)&qbuf[(size_t)(rowh0 + i) * 128 + c8];
    *(uint4*)&sKn[i * 136 + c8] = *(const uint4*)&kbuf[(size_t)(rowh0 + i) * 128 + c8];
  }
#pragma unroll
  for (int pass = 0; pass < 5; pass++) {
    int r = pass * 16 + srow;
    if (r < 67) {
      int t = t0 - 3 + r;
      uint4 v = make_uint4(0u, 0u, 0u, 0u);
      if (t >= 0) v = *(const uint4*)&mixed[(size_t)(b * Tn + t) * 3072 + 2048 + h * 128 + scol8];
      *(uint4*)&sRawV[r * 128 + scol8] = v;
    }
  }
  if (tid < 64) {
    float gv = gbuf[(size_t)(rowg0 + tid) * 8 + h];
    float bv = betabuf[(size_t)(rowg0 + tid) * 8 + h];
#pragma unroll
    for (int off = 1; off < 64; off <<= 1) {
      float o = __shfl_up(gv, off, 64);
      if (tid >= off) gv += o;
    }
    float gl = __shfl(gv, 63, 64);
    gc_s[tid] = gv;
    egc_s[tid] = expf(gv);
    bet_s[tid] = bv;
    if (tid == 63) egl[bh * 64 + n] = expf(gl);
  }
  __syncthreads();

  // ---- qg emit (overwrites this block's qn rows) ----
#pragma unroll
  for (int it = 0; it < 16; it++) {
    int idx = it * 256 + tid;
    int i = idx >> 6, d2 = (idx & 63) * 2;
    u32 w2 = *(const u32*)&sQn[i * 136 + d2];
    float e = egc_s[i];
    *(u32*)&qbuf[(size_t)(rowh0 + i) * 128 + d2] =
        pack2(bf2f(w2 & 0xffff) * e, bf2f(w2 >> 16) * e);
  }
  // ---- attn = tril(QK^T * decay) via MFMA; wave w does row band w*16.. ----
  {
    short8 qa[4];
#pragma unroll
    for (int kt = 0; kt < 4; kt++)
      qa[kt] = *(const short8*)&sQn[(wv * 16 + m16) * 136 + kt * 32 + q8];
    u16* atp = attn + (size_t)(bh * 64 + n) * 4096;
#pragma unroll
    for (int jt = 0; jt < 4; jt++) {
      int j = jt * 16 + m16;
      if (jt <= wv) {
        f32x4 o = (f32x4){0.f, 0.f, 0.f, 0.f};
#pragma unroll
        for (int kt = 0; kt < 4; kt++) {
          short8 kb = *(const short8*)&sKn[(jt * 16 + m16) * 136 + kt * 32 + q8];
          o = __builtin_amdgcn_mfma_f32_16x16x32_bf16(qa[kt], kb, o, 0, 0, 0);
        }
#pragma unroll
        for (int r = 0; r < 4; r++) {
          int i = wv * 16 + qr + r;
          float val = (j <= i) ? o[r] * expf(gc_s[i] - gc_s[j]) : 0.f;
          atp[i * 64 + j] = f2bf(val);
        }
      } else {
#pragma unroll
        for (int r = 0; r < 4; r++) atp[(wv * 16 + qr + r) * 64 + j] = 0;
      }
    }
  }
  __syncthreads();
  // ---- tri = tril(Kb K^T * decay, -1) via MFMA into triL (over sQn) ----
  {
    short8 ka[4];
#pragma unroll
    for (int kt = 0; kt < 4; kt++)
      ka[kt] = *(const short8*)&sKn[(wv * 16 + m16) * 136 + kt * 32 + q8];
#pragma unroll
    for (int jt = 0; jt < 4; jt++) {
      int j = jt * 16 + m16;
      if (jt <= wv) {
        f32x4 o = (f32x4){0.f, 0.f, 0.f, 0.f};
#pragma unroll
        for (int kt = 0; kt < 4; kt++) {
          short8 kb = *(const short8*)&sKn[(jt * 16 + m16) * 136 + kt * 32 + q8];
          o = __builtin_amdgcn_mfma_f32_16x16x32_bf16(ka[kt], kb, o, 0, 0, 0);
        }
#pragma unroll
        for (int r = 0; r < 4; r++) {
          int i = wv * 16 + qr + r;
          triL[i * 64 + j] = (j < i) ? bet_s[i] * expf(gc_s[i] - gc_s[j]) * o[r] : 0.f;
        }
      } else if (jt == wv + 1) {
#pragma unroll
        for (int r = 0; r < 4; r++) triL[(wv * 16 + qr + r) * 64 + j] = 0.f;  // solve over-read pad
      }
    }
  }
  __syncthreads();

  // ---- forward substitution: (I+tri) X = RHS, two RHS across the block ----
  {
    int mat = tid >> 7, c = tid & 127;
    float x[64];
    if (mat == 0) {
#pragma unroll
      for (int i = 0; i < 64; i++)
        x[i] = bf2f(sKn[i * 136 + c]) * bet_s[i] * egc_s[i];
    } else {
      float cwv[4];
      int colw = (2048 + h * 128 + c) * 4;
#pragma unroll
      for (int tap = 0; tap < 4; tap++) cwv[tap] = cw[colw + tap];
#pragma unroll
      for (int i = 0; i < 64; i++) {
        float a = 0.f;
#pragma unroll
        for (int tap = 0; tap < 4; tap++)
          a += bf2f(sRawV[(i + tap) * 128 + c]) * cwv[tap];
        a = a / (1.f + expf(-a));
        x[i] = a * bet_s[i];
      }
    }
    // vectorized broadcast reads; 4 independent partial sums shorten the chain
#pragma unroll
    for (int i = 1; i < 64; i++) {
      float s0 = 0.f, s1 = 0.f, s2 = 0.f, s3 = 0.f;
#pragma unroll
      for (int l4 = 0; l4 < (i + 3) / 4; l4++) {
        float4 t4 = *(float4*)&triL[i * 64 + l4 * 4];
        s0 += t4.x * x[l4 * 4 + 0];
        s1 += t4.y * x[l4 * 4 + 1];
        s2 += t4.z * x[l4 * 4 + 2];
        s3 += t4.w * x[l4 * 4 + 3];
      }
      x[i] = x[i] - ((s0 + s1) + (s2 + s3));
    }
    if (mat == 0) {
      // NEGATED kcum: scan computes vnew = v + (-kcum) @ S
#pragma unroll
      for (int i = 0; i < 64; i++) kbuf[(size_t)(rowh0 + i) * 128 + c] = f2bf(-x[i]);
    } else {
#pragma unroll
      for (int i = 0; i < 64; i += 2)
        *(u32*)&vnT[tbase + c * 64 + i] = pack2(x[i], x[i + 1]);
    }
  }
}

// ---------------------------------------------------------------------------
// MFMA inter-chunk scan v6+T5 (REVERT of v7 regression): 4 waves (256 thr);
// S state in registers; LDS carries staged operands (global_load_lds,
// coalesced) + bf16 exchanges STb/VNb. Staging split 4 ways. Barriers:
// mid lgkmcnt(0), end vmcnt(4)+lgkmcnt(0). NEW: s_setprio(1) around MFMA
// clusters (T5 — phase-split wave role diversity makes it applicable).
// Grid: 128 blocks x 256 threads. Dynamic LDS 118784 B + ~6.2 KB static.
// ---------------------------------------------------------------------------
__device__ __forceinline__ void stage_quarter(int w, u16* ldsb,
                                              const u16* __restrict__ qgc,
                                              const u16* __restrict__ kcc,
                                              const u16* __restrict__ ktc,
                                              const u16* __restrict__ atc,
                                              const u16* __restrict__ vtc,
                                              int lane) {
  int l8 = lane * 8;
  if (w == 0) {
#pragma unroll
    for (int i = 0; i < 16; i++) {
      int p = i * 512 + l8;
      async16(ldsb + 8192 + i * 512, kcc + (p ^ ((((p >> 7) & 15)) << 3)));
    }
  } else if (w == 1) {
#pragma unroll
    for (int i = 0; i < 16; i++) {
      int p = i * 512 + l8;
      async16(ldsb + 16384 + i * 512, ktc + (p ^ ((((p >> 6) & 7)) << 3)));
    }
  } else if (w == 2) {
#pragma unroll
    for (int i = 0; i < 16; i++) {
      int p = i * 512 + l8;
      async16(ldsb + i * 512, qgc + (p ^ ((((p >> 7) & 15)) << 3)));
    }
  } else {
#pragma unroll
    for (int i = 0; i < 8; i++) {
      int p = i * 512 + l8;
      async16(ldsb + 24576 + i * 512, atc + (p ^ ((((p >> 6) & 7)) << 3)));
    }
#pragma unroll
    for (int i = 0; i < 2; i++) {
      int p = i * 512 + l8;
      async16(ldsb + 28672 + i * 512, vtc + (p ^ ((((p >> 6) & 7)) << 3)));
    }
  }
}

__global__ __launch_bounds__(256, 1) void scan_mfma(const u16* __restrict__ qg,
                                                    const u16* __restrict__ kdT,
                                                    const u16* __restrict__ vnT,
                                                    const u16* __restrict__ kcum,
                                                    const u16* __restrict__ attn,
                                                    const float* __restrict__ egl,
                                                    float* __restrict__ core) {
  extern __shared__ __align__(16) u16 dyn[];
  __shared__ __align__(16) u16 STb[16 * 128];  // S^T bf16 [dv_col][dk], xor-grp swz
  __shared__ __align__(16) u16 VNb[16 * 64];   // vn  bf16 [dv_col][chunk], xor-grp swz
  int blk = blockIdx.x;
  int bh = blk & 15, tile = blk >> 4;
  int dv0 = tile * 16;
  int b = bh >> 3, h = bh & 7;
  int tid = threadIdx.x;
  int w = tid >> 6, lane = tid & 63;
  int q = lane >> 4, col = lane & 15;
  int c7 = col & 7;
  int qh = q >> 1, ql = q & 1;  // group-half decomposition of q

  // zero S^T bf16 (S starts at 0)
  for (int r = tid; r < 16 * 128 / 2; r += 256) ((u32*)STb)[r] = 0u;
  float egAll = egl[bh * 64 + lane];

  // persistent S rows in registers: wave w owns dk blocks {2w, 2w+1} (16 rows each)
  f32x4 st0 = (f32x4){0.f, 0.f, 0.f, 0.f};
  f32x4 st1 = (f32x4){0.f, 0.f, 0.f, 0.f};

  const u16* qg_base = qg + (size_t)bh * Tn * 128;
  const u16* kc_base = kcum + (size_t)bh * Tn * 128;
  const u16* kt_base = kdT + (size_t)bh * 64 * 8192;
  const u16* at_base = attn + (size_t)bh * 64 * 4096;
  const u16* vt_base = vnT + (size_t)bh * 64 * 8192 + dv0 * 64;

  stage_quarter(w, dyn, qg_base, kc_base, kt_base, at_base, vt_base, lane);
  asm volatile("s_waitcnt vmcnt(0)" ::: "memory");
  __syncthreads();

  for (int n = 0; n < 64; n++) {
    u16* buf = dyn + (n & 1) * 29696;

    // ---- phase 1: own LDS->reg fragment reads (incl. bf16 S^T) ----
    short8 kcf[4], qgf[4], ktf[4], atf[2], sb[4];
    uint2 vtf;
#pragma unroll
    for (int kt = 0; kt < 4; kt++) {
      kcf[kt] = *(const short8*)&buf[8192 + (w * 16 + col) * 128 + (((kt * 4 + q) ^ col) << 3)];
      qgf[kt] = *(const short8*)&buf[(w * 16 + col) * 128 + (((kt * 4 + q) ^ col) << 3)];
      sb[kt] = *(const short8*)&STb[col * 128 + (((kt * 4 + q) ^ col) << 3)];
    }
#pragma unroll
    for (int kt2 = 0; kt2 < 2; kt2++) {
      atf[kt2] = *(const short8*)&buf[24576 + (w * 16 + col) * 64 + (((kt2 * 4 + q) ^ c7) << 3)];
#pragma unroll
      for (int t = 0; t < 2; t++)
        ktf[t * 2 + kt2] = *(const short8*)&buf[16384 + ((w * 2 + t) * 16 + col) * 64 +
                                                (((kt2 * 4 + q) ^ c7) << 3)];
    }
    vtf = *(const uint2*)&buf[28672 + col * 64 + (((w * 2 + qh) ^ c7) << 3) + ql * 4];

    // ---- phase 2: issue own quarter of next-chunk staging ----
    if (n < 63) {
      stage_quarter(w, dyn + ((n + 1) & 1) * 29696,
                    qg_base + (size_t)(n + 1) * 8192,
                    kc_base + (size_t)(n + 1) * 8192,
                    kt_base + (size_t)(n + 1) * 8192,
                    at_base + (size_t)(n + 1) * 4096,
                    vt_base + (size_t)(n + 1) * 8192, lane);
    }
    float eg = __shfl(egAll, n, 64);

    // ---- phase 3: v_new = v + (-kcum) @ S (own 16 rows) -> bf16 -> VNb ----
    {
      f32x4 a0;
      a0[0] = bf2f(vtf.x & 0xffff); a0[1] = bf2f(vtf.x >> 16);
      a0[2] = bf2f(vtf.y & 0xffff); a0[3] = bf2f(vtf.y >> 16);
      __builtin_amdgcn_s_setprio(1);
#pragma unroll
      for (int kt = 0; kt < 4; kt++)
        a0 = __builtin_amdgcn_mfma_f32_16x16x32_bf16(kcf[kt], sb[kt], a0, 0, 0, 0);
      __builtin_amdgcn_s_setprio(0);
      uint2 pk;
      pk.x = pack2(a0[0], a0[1]);
      pk.y = pack2(a0[2], a0[3]);
      *(uint2*)&VNb[col * 64 + (((w * 2 + qh) ^ c7) << 3) + ql * 4] = pk;
    }
    // ---- mid barrier: VNb exchange + STb WAR (LDS only; prefetch in flight) ----
    asm volatile("s_waitcnt lgkmcnt(0)" ::: "memory");
    __builtin_amdgcn_s_barrier();
    __builtin_amdgcn_sched_barrier(0);

    short8 vb[2];
#pragma unroll
    for (int kt2 = 0; kt2 < 2; kt2++)
      vb[kt2] = *(const short8*)&VNb[col * 64 + (((kt2 * 4 + q) ^ c7) << 3)];

    // ---- phase 5: S = S*eg + kdT @ v_new (own 2 dk blocks, regs) -> STb ----
    __builtin_amdgcn_s_setprio(1);
    {
      f32x4 s0;
      s0[0] = st0[0] * eg; s0[1] = st0[1] * eg; s0[2] = st0[2] * eg; s0[3] = st0[3] * eg;
      s0 = __builtin_amdgcn_mfma_f32_16x16x32_bf16(ktf[0], vb[0], s0, 0, 0, 0);
      s0 = __builtin_amdgcn_mfma_f32_16x16x32_bf16(ktf[1], vb[1], s0, 0, 0, 0);
      st0 = s0;
      uint2 pk;
      pk.x = pack2(s0[0], s0[1]);
      pk.y = pack2(s0[2], s0[3]);
      *(uint2*)&STb[col * 128 + ((((w * 2 + 0) * 2 + qh) ^ col) << 3) + ql * 4] = pk;
    }
    {
      f32x4 s1;
      s1[0] = st1[0] * eg; s1[1] = st1[1] * eg; s1[2] = st1[2] * eg; s1[3] = st1[3] * eg;
      s1 = __builtin_amdgcn_mfma_f32_16x16x32_bf16(ktf[2], vb[0], s1, 0, 0, 0);
      s1 = __builtin_amdgcn_mfma_f32_16x16x32_bf16(ktf[3], vb[1], s1, 0, 0, 0);
      st1 = s1;
      uint2 pk;
      pk.x = pack2(s1[0], s1[1]);
      pk.y = pack2(s1[2], s1[3]);
      *(uint2*)&STb[col * 128 + ((((w * 2 + 1) * 2 + qh) ^ col) << 3) + ql * 4] = pk;
    }

    // ---- phase 6: out = qg @ S + attn @ v_new (own 16 rows) + stores ----
    {
      f32x4 o = (f32x4){0.f, 0.f, 0.f, 0.f};
#pragma unroll
      for (int kt = 0; kt < 4; kt++)
        o = __builtin_amdgcn_mfma_f32_16x16x32_bf16(qgf[kt], sb[kt], o, 0, 0, 0);
#pragma unroll
      for (int kt2 = 0; kt2 < 2; kt2++)
        o = __builtin_amdgcn_mfma_f32_16x16x32_bf16(atf[kt2], vb[kt2], o, 0, 0, 0);
      __builtin_amdgcn_s_setprio(0);
      size_t rowb = (size_t)(b * Tn) + n * 64 + w * 16 + q * 4;
#pragma unroll
      for (int r2 = 0; r2 < 4; r2++)
        core[(rowb + r2) * 1024 + h * 128 + dv0 + col] = o[r2];
    }

    // ---- end barrier: prefetch landed (4 stores may stay in flight),
    //      STb writes visible for next iteration's sb reads ----
    asm volatile("s_waitcnt vmcnt(4) lgkmcnt(0)" ::: "memory");
    __builtin_amdgcn_s_barrier();
    __builtin_amdgcn_sched_barrier(0);
  }
}

// ---------------------------------------------------------------------------
// Gated RMSNorm; writes bf16 coreb (A-operand of out GEMM).
// ---------------------------------------------------------------------------
__global__ __launch_bounds__(256) void gnorm(const float* __restrict__ core,
                                             const u16* __restrict__ z,
                                             const float* __restrict__ nw,
                                             u16* __restrict__ coreb) {
  __shared__ float red[256];
  __shared__ float rstd[8];
  int row = blockIdx.x, tid = threadIdx.x;
  float4 c4 = *(const float4*)&core[(size_t)row * 1024 + tid * 4];
  uint2 zl = *(const uint2*)&z[(size_t)row * 1024 + tid * 4];
  float4 z4;
  z4.x = bf2f(zl.x & 0xffff); z4.y = bf2f(zl.x >> 16);
  z4.z = bf2f(zl.y & 0xffff); z4.w = bf2f(zl.y >> 16);
  red[tid] = c4.x * c4.x + c4.y * c4.y + c4.z * c4.z + c4.w * c4.w;
  __syncthreads();
  if (tid < 8) {
    float s = 0.f;
    for (int t2 = tid * 32; t2 < tid * 32 + 32; t2++) s += red[t2];
    rstd[tid] = rsqrtf(s * (1.f / 128.f) + 1e-6f);
  }
  __syncthreads();
  float rs = rstd[tid >> 5];
  int d0 = (tid * 4) & 127;
  float4 w4 = *(const float4*)&nw[d0];
  float4 o;
  o.x = c4.x * rs * w4.x * (z4.x / (1.f + expf(-z4.x)));
  o.y = c4.y * rs * w4.y * (z4.y / (1.f + expf(-z4.y)));
  o.z = c4.z * rs * w4.z * (z4.z / (1.f + expf(-z4.z)));
  o.w = c4.w * rs * w4.w * (z4.w / (1.f + expf(-z4.w)));
  uint2 pv;
  pv.x = pack2(o.x, o.y);
  pv.y = pack2(o.z, o.w);
  *(uint2*)&coreb[(size_t)row * 1024 + tid * 4] = pv;
}

// ---------------------------------------------------------------------------
extern "C" void kernel_launch(void* const* d_in, const int* in_sizes, int n_in,
                              void* d_out, int out_size, void* d_ws, size_t ws_size,
                              hipStream_t stream) {
  const float* x     = (const float*)d_in[0];
  const float* Wqkvz = (const float*)d_in[1];
  const float* Wba   = (const float*)d_in[2];
  const float* convw = (const float*)d_in[3];
  const float* dtb   = (const float*)d_in[4];
  const float* Alog  = (const float*)d_in[5];
  const float* nw    = (const float*)d_in[6];
  const float* Wout  = (const float*)d_in[7];
  float* out = (float*)d_out;

  // Workspace layout, total 143,134,720 B. Aliases lifetime-disjoint.
  char* w = (char*)d_ws;
  u16*   mixed = (u16*)w;                      // 50,331,648 B (gemm1 out; convnorm+prep in)
  float* core  = (float*)w;                    // 33,554,432 B (aliases mixed; scan out)
  u16*   coreb = (u16*)(w + 33554432);         // 16,777,216 B (gnorm out)
  u16*   zb    = (u16*)(w + 50331648);         // 16,777,216 B
  float* betab = (float*)(w + 67108864);       //    262,144 B
  float* gb    = (float*)(w + 67371008);       //    262,144 B
  u16*   qgB   = (u16*)(w + 67633152);         // 16,777,216 B (qn from convnorm -> qg from prep)
  u16*   xb    = (u16*)(w + 67633152);         // (alias, dead before convnorm)
  u16*   kdTB  = (u16*)(w + 84410368);         // 16,777,216 B (convnorm out)
  u16*   WqT   = (u16*)(w + 84410368);         // (alias, dead before convnorm)
  u16*   vnTB  = (u16*)(w + 101187584);        // 16,777,216 B (prep out)
  u16*   kcB   = (u16*)(w + 117964800);        // 16,777,216 B (kn from convnorm -> -kcum from prep)
  u16*   WoT   = (u16*)(w + 117964800);        // (alias, written after scan)
  u16*   atB   = (u16*)(w + 134742016);        //  8,388,608 B
  float* eglB  = (float*)(w + 143130624);      //      4,096 B

  // one-time opt-in to >64KB dynamic LDS (scan ~125 KB, gemm_qkvz 128 KB)
  static bool attr_set = false;
  if (!attr_set) {
    hipFuncSetAttribute(reinterpret_cast<const void*>(scan_mfma),
                        hipFuncAttributeMaxDynamicSharedMemorySize, 118784);
    hipFuncSetAttribute(reinterpret_cast<const void*>(gemm_qkvz),
                        hipFuncAttributeMaxDynamicSharedMemorySize, 131072);
    attr_set = true;
  }

  conv_bf16<<<dim3(4096), 256, 0, stream>>>(x, xb);
  transpose_bf16<<<dim3(64, 16), 256, 0, stream>>>(Wqkvz, WqT, 1024, 4096);
  gemm_qkvz<<<dim3(512), 512, 131072, stream>>>(xb, WqT, mixed, zb);
  ba_kernel<<<dim3(8192), 128, 0, stream>>>(x, Wba, dtb, Alog, betab, gb);
  convnorm<<<dim3(64, 16, 2), 256, 0, stream>>>(mixed, convw, gb, qgB, kcB, kdTB);
  prep<<<dim3(64, 16), 256, 0, stream>>>(mixed, convw, gb, betab, qgB, kcB, vnTB, atB, eglB);
  scan_mfma<<<dim3(128), 256, 118784, stream>>>(qgB, kdTB, vnTB, kcB, atB, eglB, core);
  transpose_bf16<<<dim3(16, 16), 256, 0, stream>>>(Wout, WoT, 1024, 1024);
  gnorm<<<dim3(8192), 256, 0, stream>>>(core, zb, nw, coreb);
  gemm_mfma<0><<<dim3(8, 64), 256, 0, stream>>>(coreb, WoT, nullptr, nullptr, out, 1024);
}

// Round 10
// 394.434 us; speedup vs baseline: 1.2583x; 1.2583x over previous
//
#include <hip/hip_runtime.h>
#include <cstddef>

#define Bx 2
#define Tn 4096
#define Hh 8

typedef unsigned short u16;
typedef unsigned int u32;
typedef __attribute__((ext_vector_type(8))) short short8;
typedef __attribute__((ext_vector_type(4))) float f32x4;

__device__ __forceinline__ float bf2f(u16 u) {
  u32 x = ((u32)u) << 16;
  return __uint_as_float(x);
}
__device__ __forceinline__ u16 f2bf(float f) {
  u32 x = __float_as_uint(f);
  u32 lsb = (x >> 16) & 1;
  x += 0x7fffu + lsb;
  return (u16)(x >> 16);
}
__device__ __forceinline__ u32 pack2(float a, float b) {
  return (u32)f2bf(a) | ((u32)f2bf(b) << 16);
}
__device__ __forceinline__ short8 cvt8(float4 f0, float4 f1) {
  uint4 p;
  p.x = pack2(f0.x, f0.y);
  p.y = pack2(f0.z, f0.w);
  p.z = pack2(f1.x, f1.y);
  p.w = pack2(f1.z, f1.w);
  return *(short8*)&p;
}
__device__ __forceinline__ void async16(u16* lds, const u16* g) {
  __builtin_amdgcn_global_load_lds((const __attribute__((address_space(1))) void*)g,
                                   (__attribute__((address_space(3))) void*)lds, 16, 0, 0);
}

// ---------------------------------------------------------------------------
// f32 -> bf16 elementwise convert
// ---------------------------------------------------------------------------
__global__ __launch_bounds__(256) void conv_bf16(const float* __restrict__ X,
                                                 u16* __restrict__ Xb) {
  int i = (blockIdx.x * 256 + threadIdx.x) * 8;
  float4 v0 = *(const float4*)&X[i];
  float4 v1 = *(const float4*)&X[i + 4];
  uint4 pv;
  pv.x = pack2(v0.x, v0.y);
  pv.y = pack2(v0.z, v0.w);
  pv.z = pack2(v1.x, v1.y);
  pv.w = pack2(v1.z, v1.w);
  *(uint4*)&Xb[i] = pv;
}

// ---------------------------------------------------------------------------
// Transpose-convert: W[K][N] f32 -> WT[N][K] bf16. 64x64 tiles.
// ---------------------------------------------------------------------------
__global__ __launch_bounds__(256) void transpose_bf16(const float* __restrict__ W,
                                                      u16* __restrict__ WT,
                                                      int K, int N) {
  __shared__ float tile[64][68];
  int nb = blockIdx.x, kb = blockIdx.y;
  int tid = threadIdx.x;
  int r = tid >> 4, c4 = (tid & 15) * 4;
#pragma unroll
  for (int p = 0; p < 4; p++) {
    int k = kb * 64 + p * 16 + r;
    float4 v = *(const float4*)&W[(size_t)k * N + nb * 64 + c4];
    tile[p * 16 + r][c4] = v.x;
    tile[p * 16 + r][c4 + 1] = v.y;
    tile[p * 16 + r][c4 + 2] = v.z;
    tile[p * 16 + r][c4 + 3] = v.w;
  }
  __syncthreads();
  int rn = tid >> 2, ck = (tid & 3) * 16;
#pragma unroll
  for (int s = 0; s < 2; s++) {
    int k0 = ck + s * 8;
    uint4 pv;
    pv.x = pack2(tile[k0 + 0][rn], tile[k0 + 1][rn]);
    pv.y = pack2(tile[k0 + 2][rn], tile[k0 + 3][rn]);
    pv.z = pack2(tile[k0 + 4][rn], tile[k0 + 5][rn]);
    pv.w = pack2(tile[k0 + 6][rn], tile[k0 + 7][rn]);
    *(uint4*)&WT[(size_t)(nb * 64 + rn) * K + kb * 64 + k0] = pv;
  }
}

// ---------------------------------------------------------------------------
// gemm_qkvz: 256x256-tile deep-pipelined bf16 GEMM. 8 waves, 512 thr, BK=64.
// LDS 128 KiB dynamic, XOR-swizzled, double-buffered; one drain per K-tile.
// ---------------------------------------------------------------------------
__global__ __launch_bounds__(512, 1) void gemm_qkvz(const u16* __restrict__ A,
                                                    const u16* __restrict__ Bt,
                                                    u16* __restrict__ O1,
                                                    u16* __restrict__ O2) {
  const int K = 1024;
  extern __shared__ __align__(16) u16 gl[];  // As[2]: 0,16384; Bs[2]: 32768,49152
  int lin = blockIdx.x;
  int sl = (lin & 7) * 64 + (lin >> 3);  // 512 blocks, 64 per XCD
  int bm = sl & 31;                      // 32 M-tiles (8192/256)
  int bn = sl >> 5;                      // 16 N-tiles (4096/256); 2 per XCD
  int tid = threadIdx.x;
  int wid = tid >> 6, lane = tid & 63;
  int wm = wid >> 2, wn = wid & 3;
  int m_lane = lane & 15, kgrp = lane >> 4, m7 = m_lane & 7;

  f32x4 acc[8][4];
#pragma unroll
  for (int i = 0; i < 8; i++)
#pragma unroll
    for (int j = 0; j < 4; j++) acc[i][j] = (f32x4){0.f, 0.f, 0.f, 0.f};

  int srow = lane >> 3;
  int gc8 = ((lane & 7) ^ srow) * 8;
  const u16* Ab = A + (size_t)(bm * 256 + wid * 32 + srow) * K + gc8;
  const u16* Bb = Bt + (size_t)(bn * 256 + wid * 32 + srow) * K + gc8;

  // prologue: stage tile 0 into buffer 0
#pragma unroll
  for (int i = 0; i < 4; i++) {
    async16(gl + (wid * 32 + i * 8) * 64, Ab + (size_t)(i * 8) * K);
    async16(gl + 32768 + (wid * 32 + i * 8) * 64, Bb + (size_t)(i * 8) * K);
  }
  asm volatile("s_waitcnt vmcnt(0)" ::: "memory");
  __builtin_amdgcn_s_barrier();

  for (int t = 0; t < 16; t++) {
    int p = t & 1;
    const u16* Ap = gl + p * 16384;
    const u16* Bp = gl + 32768 + p * 16384;
    if (t < 15) {
      int pn = p ^ 1;
      int kk = (t + 1) * 64;
#pragma unroll
      for (int i = 0; i < 4; i++) {
        async16(gl + pn * 16384 + (wid * 32 + i * 8) * 64, Ab + (size_t)(i * 8) * K + kk);
        async16(gl + 32768 + pn * 16384 + (wid * 32 + i * 8) * 64, Bb + (size_t)(i * 8) * K + kk);
      }
    }
    short8 bq[2][4];
#pragma unroll
    for (int ks = 0; ks < 2; ks++)
#pragma unroll
      for (int nf = 0; nf < 4; nf++)
        bq[ks][nf] = *(const short8*)&Bp[(wn * 64 + nf * 16 + m_lane) * 64 +
                                         (((ks * 4 + kgrp) ^ m7) << 3)];
#pragma unroll
    for (int mf = 0; mf < 8; mf++) {
      short8 aq0 = *(const short8*)&Ap[(wm * 128 + mf * 16 + m_lane) * 64 +
                                       ((kgrp ^ m7) << 3)];
      short8 aq1 = *(const short8*)&Ap[(wm * 128 + mf * 16 + m_lane) * 64 +
                                       (((4 + kgrp) ^ m7) << 3)];
#pragma unroll
      for (int nf = 0; nf < 4; nf++)
        acc[mf][nf] = __builtin_amdgcn_mfma_f32_16x16x32_bf16(aq0, bq[0][nf], acc[mf][nf], 0, 0, 0);
#pragma unroll
      for (int nf = 0; nf < 4; nf++)
        acc[mf][nf] = __builtin_amdgcn_mfma_f32_16x16x32_bf16(aq1, bq[1][nf], acc[mf][nf], 0, 0, 0);
    }
    if (t < 15) {
      asm volatile("s_waitcnt vmcnt(0) lgkmcnt(0)" ::: "memory");
      __builtin_amdgcn_s_barrier();
      __builtin_amdgcn_sched_barrier(0);
    }
  }

  int n0w = bn * 256 + wn * 64;
  int h = n0w >> 9, sub = (n0w >> 7) & 3;
  int cin = ((n0w & 127) & 64) + m_lane;
  u16* dst;
  size_t stride;
  if (sub < 3) { dst = O1 + (size_t)(sub * 1024 + h * 128); stride = 3072; }
  else         { dst = O2 + (size_t)(h * 128);              stride = 1024; }
  int rbase = bm * 256 + wm * 128 + kgrp * 4;
#pragma unroll
  for (int mf = 0; mf < 8; mf++)
#pragma unroll
    for (int nf = 0; nf < 4; nf++)
#pragma unroll
      for (int r = 0; r < 4; r++)
        dst[(size_t)(rbase + mf * 16 + r) * stride + cin + nf * 16] = f2bf(acc[mf][nf][r]);
}

// ---------------------------------------------------------------------------
// bf16 MFMA GEMM v2 (128x128, BK=64, swizzled, XCD remap) — used for out GEMM.
// EPI=0: f32 store.
// ---------------------------------------------------------------------------
template<int EPI>
__global__ __launch_bounds__(256) void gemm_mfma(const u16* __restrict__ A,
                                                 const u16* __restrict__ Bt,
                                                 u16* __restrict__ O1,
                                                 u16* __restrict__ O2,
                                                 float* __restrict__ O3,
                                                 int Nfull) {
  const int K = 1024;
  __shared__ u16 As[128 * 64];
  __shared__ u16 Bs[128 * 64];
  int lin = blockIdx.y * gridDim.x + blockIdx.x;
  int sl = lin >> 3;
  int cbn = gridDim.x >> 3;
  int bn = (lin & 7) * cbn + (sl % cbn);
  int bm = sl / cbn;
  int tid = threadIdx.x;
  int wave = tid >> 6, lane = tid & 63;
  int wr = wave >> 1, wc = wave & 1;

  f32x4 acc[4][4];
#pragma unroll
  for (int i = 0; i < 4; i++)
#pragma unroll
    for (int j = 0; j < 4; j++) acc[i][j] = (f32x4){0.f, 0.f, 0.f, 0.f};

  int srow = lane >> 3;
  int gc8 = ((lane & 7) ^ srow) * 8;
  const u16* Ab = A + (size_t)(bm * 128 + wave * 32 + srow) * K + gc8;
  const u16* Bb = Bt + (size_t)(bn * 128 + wave * 32 + srow) * K + gc8;
  u16* AsW = &As[(wave * 32) * 64];
  u16* BsW = &Bs[(wave * 32) * 64];

  int m_lane = lane & 15, kgrp = lane >> 4;
  int m7 = m_lane & 7;

  for (int kk = 0; kk < K; kk += 64) {
    __syncthreads();
#pragma unroll
    for (int i = 0; i < 4; i++) {
      async16(AsW + i * 512, Ab + (size_t)(i * 8) * K + kk);
      async16(BsW + i * 512, Bb + (size_t)(i * 8) * K + kk);
    }
    __syncthreads();
    short8 a[4][2], b[4][2];
#pragma unroll
    for (int t = 0; t < 4; t++)
#pragma unroll
      for (int ks = 0; ks < 2; ks++) {
        a[t][ks] = *(const short8*)&As[(wr * 64 + t * 16 + m_lane) * 64 +
                                       (((ks * 4 + kgrp) ^ m7) << 3)];
        b[t][ks] = *(const short8*)&Bs[(wc * 64 + t * 16 + m_lane) * 64 +
                                       (((ks * 4 + kgrp) ^ m7) << 3)];
      }
#pragma unroll
    for (int ks = 0; ks < 2; ks++)
#pragma unroll
      for (int i = 0; i < 4; i++)
#pragma unroll
        for (int j = 0; j < 4; j++)
          acc[i][j] = __builtin_amdgcn_mfma_f32_16x16x32_bf16(a[i][ks], b[j][ks],
                                                              acc[i][j], 0, 0, 0);
  }

  int n0 = bn * 128;
  int cbase = wc * 64 + (lane & 15);
  int rbase = bm * 128 + wr * 64 + ((lane >> 4) * 4);
  if (EPI == 1) {
    int h = n0 >> 9, sub = (n0 >> 7) & 3;
    u16* dst;
    size_t stride;
    if (sub < 3) { dst = O1 + (size_t)(sub * 1024 + h * 128); stride = 3072; }
    else         { dst = O2 + (size_t)(h * 128);              stride = 1024; }
#pragma unroll
    for (int i = 0; i < 4; i++)
#pragma unroll
      for (int j = 0; j < 4; j++)
#pragma unroll
        for (int r = 0; r < 4; r++)
          dst[(size_t)(rbase + i * 16 + r) * stride + cbase + j * 16] = f2bf(acc[i][j][r]);
  } else {
#pragma unroll
    for (int i = 0; i < 4; i++)
#pragma unroll
      for (int j = 0; j < 4; j++)
#pragma unroll
        for (int r = 0; r < 4; r++)
          O3[(size_t)(rbase + i * 16 + r) * Nfull + n0 + cbase + j * 16] = acc[i][j][r];
  }
}

// ---------------------------------------------------------------------------
// ba = x @ W_ba then beta = sigmoid(b), g = -exp(A)*softplus(a+dt)
// ---------------------------------------------------------------------------
__global__ __launch_bounds__(128) void ba_kernel(const float* __restrict__ x,
                                                 const float* __restrict__ Wba,
                                                 const float* __restrict__ dtb,
                                                 const float* __restrict__ Alog,
                                                 float* __restrict__ betab,
                                                 float* __restrict__ gb) {
  __shared__ float xs[1024];
  __shared__ float part[8][16];
  int row = blockIdx.x, tid = threadIdx.x;
#pragma unroll
  for (int r = 0; r < 2; r++) {
    int f4 = r * 128 + tid;
    *(float4*)&xs[f4 * 4] = *(const float4*)&x[(size_t)row * 1024 + f4 * 4];
  }
  __syncthreads();
  int col = tid & 15, seg = tid >> 4;
  float a = 0.f;
  for (int k = seg * 128; k < seg * 128 + 128; k++) a += xs[k] * Wba[k * 16 + col];
  part[seg][col] = a;
  __syncthreads();
  if (tid < 8) {
    float bval = 0.f, aval = 0.f;
#pragma unroll
    for (int q = 0; q < 8; q++) { bval += part[q][tid * 2]; aval += part[q][tid * 2 + 1]; }
    betab[(size_t)row * 8 + tid] = 1.f / (1.f + expf(-bval));
    float spin = aval + dtb[tid];
    float sp = (spin > 20.f) ? spin : log1pf(expf(spin));
    gb[(size_t)row * 8 + tid] = -expf(Alog[tid]) * sp;
  }
}

// ---------------------------------------------------------------------------
// conv+silu(+l2norm) streaming kernel. type 0: q (norm), type 1: k (norm +
// kdT), type 2: v (no norm; transposed write into vbT for prep's solve).
// ---------------------------------------------------------------------------
__global__ __launch_bounds__(256) void convnorm(const u16* __restrict__ mixed,
                                                const float* __restrict__ cw,
                                                const float* __restrict__ gbuf,
                                                u16* __restrict__ qn,
                                                u16* __restrict__ kn,
                                                u16* __restrict__ kdT,
                                                u16* __restrict__ vbT) {
  __shared__ __align__(16) u16 sRaw[67 * 128];
  __shared__ __align__(16) u16 sO[64 * 136];
  __shared__ float red_s[256];
  __shared__ float inv_s[64];
  __shared__ float eglc_s[64];
  int n = blockIdx.x, bh = blockIdx.y, type = blockIdx.z;
  int b = bh >> 3, h = bh & 7;
  int t0 = n * 64, tid = threadIdx.x;
  int srow = tid >> 4, scol8 = (tid & 15) * 8;
  int base = type << 10;  // 0 q, 1024 k, 2048 v

  // stage raw slice rows t0-3..t0+63
#pragma unroll
  for (int pass = 0; pass < 5; pass++) {
    int r = pass * 16 + srow;
    if (r < 67) {
      int t = t0 - 3 + r;
      uint4 v = make_uint4(0u, 0u, 0u, 0u);
      if (t >= 0) v = *(const uint4*)&mixed[(size_t)(b * Tn + t) * 3072 + base + h * 128 + scol8];
      *(uint4*)&sRaw[r * 128 + scol8] = v;
    }
  }
  // k-type: cumsum -> eglc = exp(gl - gc_i)
  if (type == 1 && tid < 64) {
    float gv = gbuf[(size_t)(b * Tn + t0 + tid) * 8 + h];
#pragma unroll
    for (int off = 1; off < 64; off <<= 1) {
      float o = __shfl_up(gv, off, 64);
      if (tid >= off) gv += o;
    }
    float gl = __shfl(gv, 63, 64);
    eglc_s[tid] = expf(gl - gv);
  }
  __syncthreads();

  // conv + silu -> sO (bf16)
#pragma unroll
  for (int it = 0; it < 32; it++) {
    int idx = it * 256 + tid;
    int i = idx >> 7, d = idx & 127;
    int colw = (base + h * 128 + d) * 4;
    float a = 0.f;
#pragma unroll
    for (int tap = 0; tap < 4; tap++)
      a += bf2f(sRaw[(i + tap) * 128 + d]) * cw[colw + tap];
    a = a / (1.f + expf(-a));
    sO[i * 136 + d] = f2bf(a);
  }
  __syncthreads();

  if (type == 2) {
    // transposed write: vbT[bh][n][c][i] (solve consumes column-contiguous)
    const size_t tbase = (size_t)(bh * 64 + n) * 8192;
#pragma unroll
    for (int it = 0; it < 32; it++) {
      int idx = it * 256 + tid;
      int d = idx >> 6, i = idx & 63;
      vbT[tbase + d * 64 + i] = sO[i * 136 + d];
    }
    return;
  }

  // row sumsq
  {
    int i = tid >> 2, p = tid & 3;
    float ss = 0.f;
#pragma unroll
    for (int d = p * 32; d < p * 32 + 32; d += 2) {
      u32 w2 = *(const u32*)&sO[i * 136 + d];
      float a = bf2f(w2 & 0xffff), b2 = bf2f(w2 >> 16);
      ss += a * a + b2 * b2;
    }
    red_s[tid] = ss;
  }
  __syncthreads();
  if (tid < 64) {
    float inv = rsqrtf(red_s[tid * 4] + red_s[tid * 4 + 1] + red_s[tid * 4 + 2] + red_s[tid * 4 + 3] + 1e-6f);
    inv_s[tid] = (type == 0) ? inv * 0.08838834764831845f : inv;
  }
  __syncthreads();
  // normalize + emit row-major (k also writes back to LDS for kdT transpose)
  u16* dstRow = (type == 0 ? qn : kn) + (size_t)(bh * Tn + t0) * 128;
#pragma unroll
  for (int it = 0; it < 16; it++) {
    int idx = it * 256 + tid;
    int i = idx >> 6, d2 = (idx & 63) * 2;
    u32 w2 = *(const u32*)&sO[i * 136 + d2];
    float inv = inv_s[i];
    float q0 = bf2f(w2 & 0xffff) * inv, q1 = bf2f(w2 >> 16) * inv;
    u32 pk = pack2(q0, q1);
    if (type == 1) *(u32*)&sO[i * 136 + d2] = pk;
    *(u32*)&dstRow[(size_t)i * 128 + d2] = pk;
  }
  if (type == 1) {
    __syncthreads();
    const size_t tbase = (size_t)(bh * 64 + n) * 8192;
#pragma unroll
    for (int it = 0; it < 32; it++) {
      int idx = it * 256 + tid;
      int d = idx >> 6, i = idx & 63;
      kdT[tbase + d * 64 + i] = f2bf(bf2f(sO[i * 136 + d]) * eglc_s[i]);
    }
  }
}

// ---------------------------------------------------------------------------
// Per-chunk prep v4 (slimmed): stage qn/kn only (LDS 35.6 KB -> 4 blocks/CU),
// cumsum tables, qg emit, MFMA attn/tri, forward substitution. v RHS comes
// pre-conv'd/transposed from convnorm type 2 (vnT buffer, read+written
// in-place per column). kcum written NEGATED.
// ---------------------------------------------------------------------------
__global__ __launch_bounds__(256) void prep(const float* __restrict__ gbuf,
                                            const float* __restrict__ betabuf,
                                            u16* qbuf,
                                            u16* kbuf,
                                            u16* vnT,
                                            u16* __restrict__ attn,
                                            float* __restrict__ egl) {
  __shared__ __align__(16) u16 sKn[64 * 136];    // 17408 B
  __shared__ __align__(16) u16 sQn[64 * 136];    // 17408 B; aliased as tri f32[64*64]
  __shared__ float gc_s[64], egc_s[64], bet_s[64];
  float* triL = (float*)sQn;  // alias: tri written after attn consumed sQn

  int n = blockIdx.x, bh = blockIdx.y;
  int b = bh >> 3, h = bh & 7;
  int t0 = n * 64;
  int tid = threadIdx.x;
  const int rowg0 = b * Tn + t0;
  const int rowh0 = bh * Tn + t0;
  const size_t tbase = (size_t)(bh * 64 + n) * 8192;

  int wv = tid >> 6, lane = tid & 63;
  int m16 = lane & 15, q8 = (lane >> 4) * 8, qr = (lane >> 4) * 4;

  // ---- stage qn, kn (padded LDS rows) + tables ----
#pragma unroll
  for (int it = 0; it < 4; it++) {
    int idx = it * 256 + tid;
    int i = idx >> 4, c8 = (idx & 15) * 8;
    *(uint4*)&sQn[i * 136 + c8] = *(const uint4*)&qbuf[(size_t)(rowh0 + i) * 128 + c8];
    *(uint4*)&sKn[i * 136 + c8] = *(const uint4*)&kbuf[(size_t)(rowh0 + i) * 128 + c8];
  }
  if (tid < 64) {
    float gv = gbuf[(size_t)(rowg0 + tid) * 8 + h];
    float bv = betabuf[(size_t)(rowg0 + tid) * 8 + h];
#pragma unroll
    for (int off = 1; off < 64; off <<= 1) {
      float o = __shfl_up(gv, off, 64);
      if (tid >= off) gv += o;
    }
    float gl = __shfl(gv, 63, 64);
    gc_s[tid] = gv;
    egc_s[tid] = expf(gv);
    bet_s[tid] = bv;
    if (tid == 63) egl[bh * 64 + n] = expf(gl);
  }
  __syncthreads();

  // ---- qg emit (overwrites this block's qn rows) ----
#pragma unroll
  for (int it = 0; it < 16; it++) {
    int idx = it * 256 + tid;
    int i = idx >> 6, d2 = (idx & 63) * 2;
    u32 w2 = *(const u32*)&sQn[i * 136 + d2];
    float e = egc_s[i];
    *(u32*)&qbuf[(size_t)(rowh0 + i) * 128 + d2] =
        pack2(bf2f(w2 & 0xffff) * e, bf2f(w2 >> 16) * e);
  }
  // ---- attn = tril(QK^T * decay) via MFMA; wave w does row band w*16.. ----
  {
    short8 qa[4];
#pragma unroll
    for (int kt = 0; kt < 4; kt++)
      qa[kt] = *(const short8*)&sQn[(wv * 16 + m16) * 136 + kt * 32 + q8];
    u16* atp = attn + (size_t)(bh * 64 + n) * 4096;
#pragma unroll
    for (int jt = 0; jt < 4; jt++) {
      int j = jt * 16 + m16;
      if (jt <= wv) {
        f32x4 o = (f32x4){0.f, 0.f, 0.f, 0.f};
#pragma unroll
        for (int kt = 0; kt < 4; kt++) {
          short8 kb = *(const short8*)&sKn[(jt * 16 + m16) * 136 + kt * 32 + q8];
          o = __builtin_amdgcn_mfma_f32_16x16x32_bf16(qa[kt], kb, o, 0, 0, 0);
        }
#pragma unroll
        for (int r = 0; r < 4; r++) {
          int i = wv * 16 + qr + r;
          float val = (j <= i) ? o[r] * expf(gc_s[i] - gc_s[j]) : 0.f;
          atp[i * 64 + j] = f2bf(val);
        }
      } else {
#pragma unroll
        for (int r = 0; r < 4; r++) atp[(wv * 16 + qr + r) * 64 + j] = 0;
      }
    }
  }
  __syncthreads();
  // ---- tri = tril(Kb K^T * decay, -1) via MFMA into triL (over sQn) ----
  {
    short8 ka[4];
#pragma unroll
    for (int kt = 0; kt < 4; kt++)
      ka[kt] = *(const short8*)&sKn[(wv * 16 + m16) * 136 + kt * 32 + q8];
#pragma unroll
    for (int jt = 0; jt < 4; jt++) {
      int j = jt * 16 + m16;
      if (jt <= wv) {
        f32x4 o = (f32x4){0.f, 0.f, 0.f, 0.f};
#pragma unroll
        for (int kt = 0; kt < 4; kt++) {
          short8 kb = *(const short8*)&sKn[(jt * 16 + m16) * 136 + kt * 32 + q8];
          o = __builtin_amdgcn_mfma_f32_16x16x32_bf16(ka[kt], kb, o, 0, 0, 0);
        }
#pragma unroll
        for (int r = 0; r < 4; r++) {
          int i = wv * 16 + qr + r;
          triL[i * 64 + j] = (j < i) ? bet_s[i] * expf(gc_s[i] - gc_s[j]) * o[r] : 0.f;
        }
      } else if (jt == wv + 1) {
#pragma unroll
        for (int r = 0; r < 4; r++) triL[(wv * 16 + qr + r) * 64 + j] = 0.f;  // solve over-read pad
      }
    }
  }
  __syncthreads();

  // ---- forward substitution: (I+tri) X = RHS, two RHS across the block ----
  {
    int mat = tid >> 7, c = tid & 127;
    float x[64];
    if (mat == 0) {
#pragma unroll
      for (int i = 0; i < 64; i++)
        x[i] = bf2f(sKn[i * 136 + c]) * bet_s[i] * egc_s[i];
    } else {
      // RHS = conv'd/silu'd v (from convnorm type 2) * beta, column-contiguous
#pragma unroll
      for (int i8 = 0; i8 < 8; i8++) {
        short8 vv = *(const short8*)&vnT[tbase + c * 64 + i8 * 8];
#pragma unroll
        for (int j = 0; j < 8; j++)
          x[i8 * 8 + j] = bf2f((u16)vv[j]) * bet_s[i8 * 8 + j];
      }
    }
    // vectorized broadcast reads; 4 independent partial sums shorten the chain
#pragma unroll
    for (int i = 1; i < 64; i++) {
      float s0 = 0.f, s1 = 0.f, s2 = 0.f, s3 = 0.f;
#pragma unroll
      for (int l4 = 0; l4 < (i + 3) / 4; l4++) {
        float4 t4 = *(float4*)&triL[i * 64 + l4 * 4];
        s0 += t4.x * x[l4 * 4 + 0];
        s1 += t4.y * x[l4 * 4 + 1];
        s2 += t4.z * x[l4 * 4 + 2];
        s3 += t4.w * x[l4 * 4 + 3];
      }
      x[i] = x[i] - ((s0 + s1) + (s2 + s3));
    }
    if (mat == 0) {
      // NEGATED kcum: scan computes vnew = v + (-kcum) @ S
#pragma unroll
      for (int i = 0; i < 64; i++) kbuf[(size_t)(rowh0 + i) * 128 + c] = f2bf(-x[i]);
    } else {
      // in-place: same column this thread read above
#pragma unroll
      for (int i = 0; i < 64; i += 2)
        *(u32*)&vnT[tbase + c * 64 + i] = pack2(x[i], x[i + 1]);
    }
  }
}

// ---------------------------------------------------------------------------
// MFMA inter-chunk scan v6 (known-good): 4 waves (256 thr); S in registers;
// LDS staged operands (global_load_lds) + bf16 exchanges STb/VNb.
// Barriers: mid lgkmcnt(0), end vmcnt(4)+lgkmcnt(0).
// Grid: 128 blocks x 256 threads. Dynamic LDS 118784 B + ~6.2 KB static.
// ---------------------------------------------------------------------------
__device__ __forceinline__ void stage_quarter(int w, u16* ldsb,
                                              const u16* __restrict__ qgc,
                                              const u16* __restrict__ kcc,
                                              const u16* __restrict__ ktc,
                                              const u16* __restrict__ atc,
                                              const u16* __restrict__ vtc,
                                              int lane) {
  int l8 = lane * 8;
  if (w == 0) {
#pragma unroll
    for (int i = 0; i < 16; i++) {
      int p = i * 512 + l8;
      async16(ldsb + 8192 + i * 512, kcc + (p ^ ((((p >> 7) & 15)) << 3)));
    }
  } else if (w == 1) {
#pragma unroll
    for (int i = 0; i < 16; i++) {
      int p = i * 512 + l8;
      async16(ldsb + 16384 + i * 512, ktc + (p ^ ((((p >> 6) & 7)) << 3)));
    }
  } else if (w == 2) {
#pragma unroll
    for (int i = 0; i < 16; i++) {
      int p = i * 512 + l8;
      async16(ldsb + i * 512, qgc + (p ^ ((((p >> 7) & 15)) << 3)));
    }
  } else {
#pragma unroll
    for (int i = 0; i < 8; i++) {
      int p = i * 512 + l8;
      async16(ldsb + 24576 + i * 512, atc + (p ^ ((((p >> 6) & 7)) << 3)));
    }
#pragma unroll
    for (int i = 0; i < 2; i++) {
      int p = i * 512 + l8;
      async16(ldsb + 28672 + i * 512, vtc + (p ^ ((((p >> 6) & 7)) << 3)));
    }
  }
}

__global__ __launch_bounds__(256, 1) void scan_mfma(const u16* __restrict__ qg,
                                                    const u16* __restrict__ kdT,
                                                    const u16* __restrict__ vnT,
                                                    const u16* __restrict__ kcum,
                                                    const u16* __restrict__ attn,
                                                    const float* __restrict__ egl,
                                                    float* __restrict__ core) {
  extern __shared__ __align__(16) u16 dyn[];
  __shared__ __align__(16) u16 STb[16 * 128];  // S^T bf16 [dv_col][dk], xor-grp swz
  __shared__ __align__(16) u16 VNb[16 * 64];   // vn  bf16 [dv_col][chunk], xor-grp swz
  int blk = blockIdx.x;
  int bh = blk & 15, tile = blk >> 4;
  int dv0 = tile * 16;
  int b = bh >> 3, h = bh & 7;
  int tid = threadIdx.x;
  int w = tid >> 6, lane = tid & 63;
  int q = lane >> 4, col = lane & 15;
  int c7 = col & 7;
  int qh = q >> 1, ql = q & 1;  // group-half decomposition of q

  // zero S^T bf16 (S starts at 0)
  for (int r = tid; r < 16 * 128 / 2; r += 256) ((u32*)STb)[r] = 0u;
  float egAll = egl[bh * 64 + lane];

  // persistent S rows in registers: wave w owns dk blocks {2w, 2w+1} (16 rows each)
  f32x4 st0 = (f32x4){0.f, 0.f, 0.f, 0.f};
  f32x4 st1 = (f32x4){0.f, 0.f, 0.f, 0.f};

  const u16* qg_base = qg + (size_t)bh * Tn * 128;
  const u16* kc_base = kcum + (size_t)bh * Tn * 128;
  const u16* kt_base = kdT + (size_t)bh * 64 * 8192;
  const u16* at_base = attn + (size_t)bh * 64 * 4096;
  const u16* vt_base = vnT + (size_t)bh * 64 * 8192 + dv0 * 64;

  stage_quarter(w, dyn, qg_base, kc_base, kt_base, at_base, vt_base, lane);
  asm volatile("s_waitcnt vmcnt(0)" ::: "memory");
  __syncthreads();

  for (int n = 0; n < 64; n++) {
    u16* buf = dyn + (n & 1) * 29696;

    // ---- phase 1: own LDS->reg fragment reads (incl. bf16 S^T) ----
    short8 kcf[4], qgf[4], ktf[4], atf[2], sb[4];
    uint2 vtf;
#pragma unroll
    for (int kt = 0; kt < 4; kt++) {
      kcf[kt] = *(const short8*)&buf[8192 + (w * 16 + col) * 128 + (((kt * 4 + q) ^ col) << 3)];
      qgf[kt] = *(const short8*)&buf[(w * 16 + col) * 128 + (((kt * 4 + q) ^ col) << 3)];
      sb[kt] = *(const short8*)&STb[col * 128 + (((kt * 4 + q) ^ col) << 3)];
    }
#pragma unroll
    for (int kt2 = 0; kt2 < 2; kt2++) {
      atf[kt2] = *(const short8*)&buf[24576 + (w * 16 + col) * 64 + (((kt2 * 4 + q) ^ c7) << 3)];
#pragma unroll
      for (int t = 0; t < 2; t++)
        ktf[t * 2 + kt2] = *(const short8*)&buf[16384 + ((w * 2 + t) * 16 + col) * 64 +
                                                (((kt2 * 4 + q) ^ c7) << 3)];
    }
    vtf = *(const uint2*)&buf[28672 + col * 64 + (((w * 2 + qh) ^ c7) << 3) + ql * 4];

    // ---- phase 2: issue own quarter of next-chunk staging ----
    if (n < 63) {
      stage_quarter(w, dyn + ((n + 1) & 1) * 29696,
                    qg_base + (size_t)(n + 1) * 8192,
                    kc_base + (size_t)(n + 1) * 8192,
                    kt_base + (size_t)(n + 1) * 8192,
                    at_base + (size_t)(n + 1) * 4096,
                    vt_base + (size_t)(n + 1) * 8192, lane);
    }
    float eg = __shfl(egAll, n, 64);

    // ---- phase 3: v_new = v + (-kcum) @ S (own 16 rows) -> bf16 -> VNb ----
    {
      f32x4 a0;
      a0[0] = bf2f(vtf.x & 0xffff); a0[1] = bf2f(vtf.x >> 16);
      a0[2] = bf2f(vtf.y & 0xffff); a0[3] = bf2f(vtf.y >> 16);
#pragma unroll
      for (int kt = 0; kt < 4; kt++)
        a0 = __builtin_amdgcn_mfma_f32_16x16x32_bf16(kcf[kt], sb[kt], a0, 0, 0, 0);
      uint2 pk;
      pk.x = pack2(a0[0], a0[1]);
      pk.y = pack2(a0[2], a0[3]);
      *(uint2*)&VNb[col * 64 + (((w * 2 + qh) ^ c7) << 3) + ql * 4] = pk;
    }
    // ---- mid barrier: VNb exchange + STb WAR (LDS only; prefetch in flight) ----
    asm volatile("s_waitcnt lgkmcnt(0)" ::: "memory");
    __builtin_amdgcn_s_barrier();
    __builtin_amdgcn_sched_barrier(0);

    short8 vb[2];
#pragma unroll
    for (int kt2 = 0; kt2 < 2; kt2++)
      vb[kt2] = *(const short8*)&VNb[col * 64 + (((kt2 * 4 + q) ^ c7) << 3)];

    // ---- phase 5: S = S*eg + kdT @ v_new (own 2 dk blocks, regs) -> STb ----
    {
      f32x4 s0;
      s0[0] = st0[0] * eg; s0[1] = st0[1] * eg; s0[2] = st0[2] * eg; s0[3] = st0[3] * eg;
      s0 = __builtin_amdgcn_mfma_f32_16x16x32_bf16(ktf[0], vb[0], s0, 0, 0, 0);
      s0 = __builtin_amdgcn_mfma_f32_16x16x32_bf16(ktf[1], vb[1], s0, 0, 0, 0);
      st0 = s0;
      uint2 pk;
      pk.x = pack2(s0[0], s0[1]);
      pk.y = pack2(s0[2], s0[3]);
      *(uint2*)&STb[col * 128 + ((((w * 2 + 0) * 2 + qh) ^ col) << 3) + ql * 4] = pk;
    }
    {
      f32x4 s1;
      s1[0] = st1[0] * eg; s1[1] = st1[1] * eg; s1[2] = st1[2] * eg; s1[3] = st1[3] * eg;
      s1 = __builtin_amdgcn_mfma_f32_16x16x32_bf16(ktf[2], vb[0], s1, 0, 0, 0);
      s1 = __builtin_amdgcn_mfma_f32_16x16x32_bf16(ktf[3], vb[1], s1, 0, 0, 0);
      st1 = s1;
      uint2 pk;
      pk.x = pack2(s1[0], s1[1]);
      pk.y = pack2(s1[2], s1[3]);
      *(uint2*)&STb[col * 128 + ((((w * 2 + 1) * 2 + qh) ^ col) << 3) + ql * 4] = pk;
    }

    // ---- phase 6: out = qg @ S + attn @ v_new (own 16 rows) + stores ----
    {
      f32x4 o = (f32x4){0.f, 0.f, 0.f, 0.f};
#pragma unroll
      for (int kt = 0; kt < 4; kt++)
        o = __builtin_amdgcn_mfma_f32_16x16x32_bf16(qgf[kt], sb[kt], o, 0, 0, 0);
#pragma unroll
      for (int kt2 = 0; kt2 < 2; kt2++)
        o = __builtin_amdgcn_mfma_f32_16x16x32_bf16(atf[kt2], vb[kt2], o, 0, 0, 0);
      size_t rowb = (size_t)(b * Tn) + n * 64 + w * 16 + q * 4;
#pragma unroll
      for (int r2 = 0; r2 < 4; r2++)
        core[(rowb + r2) * 1024 + h * 128 + dv0 + col] = o[r2];
    }

    // ---- end barrier: prefetch landed (4 stores may stay in flight),
    //      STb writes visible for next iteration's sb reads ----
    asm volatile("s_waitcnt vmcnt(4) lgkmcnt(0)" ::: "memory");
    __builtin_amdgcn_s_barrier();
    __builtin_amdgcn_sched_barrier(0);
  }
}

// ---------------------------------------------------------------------------
// Gated RMSNorm; writes bf16 coreb (A-operand of out GEMM).
// ---------------------------------------------------------------------------
__global__ __launch_bounds__(256) void gnorm(const float* __restrict__ core,
                                             const u16* __restrict__ z,
                                             const float* __restrict__ nw,
                                             u16* __restrict__ coreb) {
  __shared__ float red[256];
  __shared__ float rstd[8];
  int row = blockIdx.x, tid = threadIdx.x;
  float4 c4 = *(const float4*)&core[(size_t)row * 1024 + tid * 4];
  uint2 zl = *(const uint2*)&z[(size_t)row * 1024 + tid * 4];
  float4 z4;
  z4.x = bf2f(zl.x & 0xffff); z4.y = bf2f(zl.x >> 16);
  z4.z = bf2f(zl.y & 0xffff); z4.w = bf2f(zl.y >> 16);
  red[tid] = c4.x * c4.x + c4.y * c4.y + c4.z * c4.z + c4.w * c4.w;
  __syncthreads();
  if (tid < 8) {
    float s = 0.f;
    for (int t2 = tid * 32; t2 < tid * 32 + 32; t2++) s += red[t2];
    rstd[tid] = rsqrtf(s * (1.f / 128.f) + 1e-6f);
  }
  __syncthreads();
  float rs = rstd[tid >> 5];
  int d0 = (tid * 4) & 127;
  float4 w4 = *(const float4*)&nw[d0];
  float4 o;
  o.x = c4.x * rs * w4.x * (z4.x / (1.f + expf(-z4.x)));
  o.y = c4.y * rs * w4.y * (z4.y / (1.f + expf(-z4.y)));
  o.z = c4.z * rs * w4.z * (z4.z / (1.f + expf(-z4.z)));
  o.w = c4.w * rs * w4.w * (z4.w / (1.f + expf(-z4.w)));
  uint2 pv;
  pv.x = pack2(o.x, o.y);
  pv.y = pack2(o.z, o.w);
  *(uint2*)&coreb[(size_t)row * 1024 + tid * 4] = pv;
}

// ---------------------------------------------------------------------------
extern "C" void kernel_launch(void* const* d_in, const int* in_sizes, int n_in,
                              void* d_out, int out_size, void* d_ws, size_t ws_size,
                              hipStream_t stream) {
  const float* x     = (const float*)d_in[0];
  const float* Wqkvz = (const float*)d_in[1];
  const float* Wba   = (const float*)d_in[2];
  const float* convw = (const float*)d_in[3];
  const float* dtb   = (const float*)d_in[4];
  const float* Alog  = (const float*)d_in[5];
  const float* nw    = (const float*)d_in[6];
  const float* Wout  = (const float*)d_in[7];
  float* out = (float*)d_out;

  // Workspace layout, total 143,134,720 B. Aliases lifetime-disjoint.
  char* w = (char*)d_ws;
  u16*   mixed = (u16*)w;                      // 50,331,648 B (gemm1 out; convnorm in)
  float* core  = (float*)w;                    // 33,554,432 B (aliases mixed; scan out)
  u16*   coreb = (u16*)(w + 33554432);         // 16,777,216 B (gnorm out)
  u16*   zb    = (u16*)(w + 50331648);         // 16,777,216 B
  float* betab = (float*)(w + 67108864);       //    262,144 B
  float* gb    = (float*)(w + 67371008);       //    262,144 B
  u16*   qgB   = (u16*)(w + 67633152);         // 16,777,216 B (qn -> qg)
  u16*   xb    = (u16*)(w + 67633152);         // (alias, dead before convnorm)
  u16*   kdTB  = (u16*)(w + 84410368);         // 16,777,216 B (convnorm out)
  u16*   WqT   = (u16*)(w + 84410368);         // (alias, dead before convnorm)
  u16*   vnTB  = (u16*)(w + 101187584);        // 16,777,216 B (conv'd v -> solve out, in-place)
  u16*   kcB   = (u16*)(w + 117964800);        // 16,777,216 B (kn -> -kcum)
  u16*   WoT   = (u16*)(w + 117964800);        // (alias, written after scan)
  u16*   atB   = (u16*)(w + 134742016);        //  8,388,608 B
  float* eglB  = (float*)(w + 143130624);      //      4,096 B

  // one-time opt-in to >64KB dynamic LDS (scan ~125 KB, gemm_qkvz 128 KB)
  static bool attr_set = false;
  if (!attr_set) {
    hipFuncSetAttribute(reinterpret_cast<const void*>(scan_mfma),
                        hipFuncAttributeMaxDynamicSharedMemorySize, 118784);
    hipFuncSetAttribute(reinterpret_cast<const void*>(gemm_qkvz),
                        hipFuncAttributeMaxDynamicSharedMemorySize, 131072);
    attr_set = true;
  }

  conv_bf16<<<dim3(4096), 256, 0, stream>>>(x, xb);
  transpose_bf16<<<dim3(64, 16), 256, 0, stream>>>(Wqkvz, WqT, 1024, 4096);
  gemm_qkvz<<<dim3(512), 512, 131072, stream>>>(xb, WqT, mixed, zb);
  ba_kernel<<<dim3(8192), 128, 0, stream>>>(x, Wba, dtb, Alog, betab, gb);
  convnorm<<<dim3(64, 16, 3), 256, 0, stream>>>(mixed, convw, gb, qgB, kcB, kdTB, vnTB);
  prep<<<dim3(64, 16), 256, 0, stream>>>(gb, betab, qgB, kcB, vnTB, atB, eglB);
  scan_mfma<<<dim3(128), 256, 118784, stream>>>(qgB, kdTB, vnTB, kcB, atB, eglB, core);
  transpose_bf16<<<dim3(16, 16), 256, 0, stream>>>(Wout, WoT, 1024, 1024);
  gnorm<<<dim3(8192), 256, 0, stream>>>(core, zb, nw, coreb);
  gemm_mfma<0><<<dim3(8, 64), 256, 0, stream>>>(coreb, WoT, nullptr, nullptr, out, 1024);
}